// Round 7
// baseline (261.316 us; speedup 1.0000x reference)
//
#include <hip/hip_runtime.h>

#define D 128
#define BN_EPS 1e-5f

typedef __attribute__((ext_vector_type(8))) short short8;
typedef __attribute__((ext_vector_type(4))) float f32x4;

// float -> bf16 bits, round-to-nearest-even
__device__ inline unsigned short f2bf(float f) {
    union { float f; unsigned int u; } v; v.f = f;
    unsigned int u = v.u;
    unsigned int r = (u + 0x7FFFu + ((u >> 16) & 1u)) >> 16;
    return (unsigned short)r;
}

__device__ inline float bfbits2f(unsigned int bits) {
    union { unsigned int u; float f; } v; v.u = bits;
    return v.f;
}

__device__ inline float4 bf2f4(uint2 v) {
    float4 r;
    r.x = bfbits2f(v.x << 16);
    r.y = bfbits2f(v.x & 0xFFFF0000u);
    r.z = bfbits2f(v.y << 16);
    r.w = bfbits2f(v.y & 0xFFFF0000u);
    return r;
}

// ------------------------------- histogram + per-edge rank (coalesced write)
__global__ void hist_rank(const int* __restrict__ dst, int* __restrict__ cnt,
                          int* __restrict__ rank, int E) {
    int e = blockIdx.x * blockDim.x + threadIdx.x;
    if (e >= E) return;
    rank[e] = atomicAdd(&cnt[dst[e]], 1);
}

// -------------------------------------------------- scan phase 1: per-block reduce
__global__ void reduce_cnt(const int* __restrict__ cnt, int* __restrict__ bsum, int n) {
    __shared__ int s[256];
    int tid = threadIdx.x;
    int i = blockIdx.x * 256 + tid;
    s[tid] = (i < n) ? cnt[i] : 0;
    __syncthreads();
    for (int ofs = 128; ofs > 0; ofs >>= 1) {
        if (tid < ofs) s[tid] += s[tid + ofs];
        __syncthreads();
    }
    if (tid == 0) bsum[blockIdx.x] = s[0];
}

// -------------------------------------------------- scan phase 2: scan block sums (1 block)
__global__ void scan_bsums(const int* __restrict__ bsum, int* __restrict__ blockOff,
                           int* __restrict__ offN, int nb) {
    __shared__ int s[256];
    int tid = threadIdx.x;
    int v = (tid < nb) ? bsum[tid] : 0;
    s[tid] = v;
    __syncthreads();
    for (int ofs = 1; ofs < 256; ofs <<= 1) {
        int t = (tid >= ofs) ? s[tid - ofs] : 0;
        __syncthreads();
        s[tid] += t;
        __syncthreads();
    }
    if (tid < nb) blockOff[tid] = s[tid] - v;
    if (tid == nb - 1) *offN = s[tid];
}

// -------------------------------------------------- scan phase 3: per-block scan + offset
__global__ void scan_partial(const int* __restrict__ cnt, int* __restrict__ off,
                             const int* __restrict__ blockOff, int n) {
    __shared__ int s[256];
    int tid = threadIdx.x;
    int i = blockIdx.x * 256 + tid;
    int v = (i < n) ? cnt[i] : 0;
    s[tid] = v;
    __syncthreads();
    for (int ofs = 1; ofs < 256; ofs <<= 1) {
        int t = (tid >= ofs) ? s[tid - ofs] : 0;
        __syncthreads();
        s[tid] += t;
        __syncthreads();
    }
    if (i < n) off[i] = blockOff[blockIdx.x] + s[tid] - v;
}

// -------------------------------------------------- CSR fill (no atomics)
template<typename IdxT>
__global__ void fill2(const int* __restrict__ src, const int* __restrict__ dst,
                      const int* __restrict__ rank, const int* __restrict__ off,
                      IdxT* __restrict__ eidx, int E) {
    int e = blockIdx.x * blockDim.x + threadIdx.x;
    if (e >= E) return;
    eidx[off[dst[e]] + rank[e]] = (IdxT)src[e];
}

// ------------------------- weight prep: Wt[m][n][k] = bf16(W[m][k][n]), m = 2L mats
__global__ void wprep(const float* __restrict__ W1, const float* __restrict__ W2,
                      unsigned short* __restrict__ Wt, int L) {
    int idx = blockIdx.x * 256 + threadIdx.x;
    int m = idx >> 14;
    int rem = idx & 16383;
    int c = rem >> 7, k = rem & 127;
    const float* W = (m < L) ? (W1 + (size_t)m * D * D) : (W2 + (size_t)(m - L) * D * D);
    Wt[(size_t)m * D * D + c * D + k] = f2bf(W[k * D + c]);
}

// -------------------------------------------------- h (fp32) -> xb (bf16)
__global__ void x2bf(const float* __restrict__ x, unsigned short* __restrict__ xb, int n8) {
    int i = blockIdx.x * 256 + threadIdx.x;
    if (i >= n8) return;
    float4 a = reinterpret_cast<const float4*>(x)[2 * i];
    float4 b = reinterpret_cast<const float4*>(x)[2 * i + 1];
    uint4 o;
    o.x = (unsigned)f2bf(a.x) | ((unsigned)f2bf(a.y) << 16);
    o.y = (unsigned)f2bf(a.z) | ((unsigned)f2bf(a.w) << 16);
    o.z = (unsigned)f2bf(b.x) | ((unsigned)f2bf(b.y) << 16);
    o.w = (unsigned)f2bf(b.z) | ((unsigned)f2bf(b.w) << 16);
    reinterpret_cast<uint4*>(xb)[i] = o;
}

// ------------------------------ z_i = x_i + sum_{j in N(i)} x_j, bf16 in / bf16 out
// XCD-sliced: slice = blockIdx & 3 covers cols [slice*32, slice*32+32) = one 64B
// line per row. With round-robin block->XCD dispatch, each XCD's L2 only sees a
// 3.2MB slice of xb -> fits 4MB L2 -> edge row reads become L2 hits.
// 8 lanes per node per slice (uint2 = 8B each).
template<typename IdxT>
__global__ __launch_bounds__(256) void gather_bf4(
        const unsigned short* __restrict__ xb, const int* __restrict__ off,
        const IdxT* __restrict__ eidx, unsigned short* __restrict__ zb, int N) {
    const int slice = blockIdx.x & 3;
    const int node = (blockIdx.x >> 2) * 32 + (threadIdx.x >> 3);
    if (node >= N) return;
    const int lane8 = threadIdx.x & 7;
    const int colOfs = slice * 32 + lane8 * 4;          // in bf16 elements
    const unsigned short* base = xb + colOfs;

    float4 acc = bf2f4(*reinterpret_cast<const uint2*>(base + (size_t)node * D));
    int beg = off[node], end = off[node + 1];
    int e = beg;
    for (; e + 2 <= end; e += 2) {
        int s0 = (int)eidx[e], s1 = (int)eidx[e + 1];
        uint2 v0 = *reinterpret_cast<const uint2*>(base + (size_t)s0 * D);
        uint2 v1 = *reinterpret_cast<const uint2*>(base + (size_t)s1 * D);
        float4 f0 = bf2f4(v0), f1 = bf2f4(v1);
        acc.x += f0.x + f1.x; acc.y += f0.y + f1.y;
        acc.z += f0.z + f1.z; acc.w += f0.w + f1.w;
    }
    if (e < end) {
        int s0 = (int)eidx[e];
        float4 f0 = bf2f4(*reinterpret_cast<const uint2*>(base + (size_t)s0 * D));
        acc.x += f0.x; acc.y += f0.y; acc.z += f0.z; acc.w += f0.w;
    }
    uint2 o;
    o.x = (unsigned)f2bf(acc.x) | ((unsigned)f2bf(acc.y) << 16);
    o.y = (unsigned)f2bf(acc.z) | ((unsigned)f2bf(acc.w) << 16);
    *reinterpret_cast<uint2*>(zb + (size_t)node * D + colOfs) = o;
}

// ------------- MFMA GEMM1, no LDS: zb = relu(zb@W1 + b1), 128 rows/block,
// 4 waves x 2 row-tiles; B-fragments stream from L2 (Wt is 32KB, grid-broadcast).
__global__ __launch_bounds__(256) void gemm1_mfma(
        const unsigned short* __restrict__ A, const unsigned short* __restrict__ Wt,
        const float* __restrict__ bias, unsigned short* __restrict__ Out, int N) {
    const int tid = threadIdx.x;
    const int lane = tid & 63, wv = tid >> 6;
    const int r0 = blockIdx.x * 128 + wv * 32;
    const int koff = (lane >> 4) << 3;
    const int col = lane & 15;

    int ar0 = r0 + col;       if (ar0 >= N) ar0 = N - 1;
    int ar1 = r0 + 16 + col;  if (ar1 >= N) ar1 = N - 1;
    const unsigned short* ap0 = A + (size_t)ar0 * D + koff;
    const unsigned short* ap1 = A + (size_t)ar1 * D + koff;
    const unsigned short* wp  = Wt + (size_t)col * D + koff;

    f32x4 acc[2][8];
    #pragma unroll
    for (int ct = 0; ct < 8; ct++) {
        float b = bias[ct * 16 + col];
        acc[0][ct] = (f32x4){b, b, b, b};
        acc[1][ct] = (f32x4){b, b, b, b};
    }
    #pragma unroll
    for (int ks = 0; ks < 4; ks++) {
        short8 a0 = *reinterpret_cast<const short8*>(ap0 + ks * 32);
        short8 a1 = *reinterpret_cast<const short8*>(ap1 + ks * 32);
        #pragma unroll
        for (int ct = 0; ct < 8; ct++) {
            short8 bfr = *reinterpret_cast<const short8*>(wp + (size_t)ct * 16 * D + ks * 32);
            acc[0][ct] = __builtin_amdgcn_mfma_f32_16x16x32_bf16(a0, bfr, acc[0][ct], 0, 0, 0);
            acc[1][ct] = __builtin_amdgcn_mfma_f32_16x16x32_bf16(a1, bfr, acc[1][ct], 0, 0, 0);
        }
    }
    #pragma unroll
    for (int t = 0; t < 2; t++) {
        #pragma unroll
        for (int ct = 0; ct < 8; ct++) {
            #pragma unroll
            for (int r = 0; r < 4; r++) {
                int row = r0 + t * 16 + ((lane >> 4) << 2) + r;
                if (row < N)
                    Out[(size_t)row * D + ct * 16 + col] = f2bf(fmaxf(acc[t][ct][r], 0.f));
            }
        }
    }
}

// ------------- MFMA GEMM2, no LDS: y = zb@W2 + b2 (fp32 out) + column stats
__global__ __launch_bounds__(256) void gemm2_mfma(
        const unsigned short* __restrict__ A, const unsigned short* __restrict__ Wt,
        const float* __restrict__ bias, float* __restrict__ Out,
        float* __restrict__ gstats, int N) {
    __shared__ float sStat[2 * D];
    const int tid = threadIdx.x;
    if (tid < 2 * D) sStat[tid] = 0.f;
    __syncthreads();

    const int lane = tid & 63, wv = tid >> 6;
    const int r0 = blockIdx.x * 128 + wv * 32;
    const int koff = (lane >> 4) << 3;
    const int col = lane & 15;

    int ar0 = r0 + col;       if (ar0 >= N) ar0 = N - 1;
    int ar1 = r0 + 16 + col;  if (ar1 >= N) ar1 = N - 1;
    const unsigned short* ap0 = A + (size_t)ar0 * D + koff;
    const unsigned short* ap1 = A + (size_t)ar1 * D + koff;
    const unsigned short* wp  = Wt + (size_t)col * D + koff;

    f32x4 acc[2][8];
    #pragma unroll
    for (int ct = 0; ct < 8; ct++) {
        float b = bias[ct * 16 + col];
        acc[0][ct] = (f32x4){b, b, b, b};
        acc[1][ct] = (f32x4){b, b, b, b};
    }
    #pragma unroll
    for (int ks = 0; ks < 4; ks++) {
        short8 a0 = *reinterpret_cast<const short8*>(ap0 + ks * 32);
        short8 a1 = *reinterpret_cast<const short8*>(ap1 + ks * 32);
        #pragma unroll
        for (int ct = 0; ct < 8; ct++) {
            short8 bfr = *reinterpret_cast<const short8*>(wp + (size_t)ct * 16 * D + ks * 32);
            acc[0][ct] = __builtin_amdgcn_mfma_f32_16x16x32_bf16(a0, bfr, acc[0][ct], 0, 0, 0);
            acc[1][ct] = __builtin_amdgcn_mfma_f32_16x16x32_bf16(a1, bfr, acc[1][ct], 0, 0, 0);
        }
    }
    #pragma unroll
    for (int ct = 0; ct < 8; ct++) {
        float s = 0.f, q = 0.f;
        #pragma unroll
        for (int t = 0; t < 2; t++) {
            #pragma unroll
            for (int r = 0; r < 4; r++) {
                int row = r0 + t * 16 + ((lane >> 4) << 2) + r;
                float v = acc[t][ct][r];
                if (row < N) {
                    Out[(size_t)row * D + ct * 16 + col] = v;
                    s += v; q += v * v;
                }
            }
        }
        s += __shfl_xor(s, 16); q += __shfl_xor(q, 16);
        s += __shfl_xor(s, 32); q += __shfl_xor(q, 32);
        if (lane < 16) {
            atomicAdd(&sStat[ct * 16 + lane], s);
            atomicAdd(&sStat[D + ct * 16 + lane], q);
        }
    }
    __syncthreads();
    if (tid < 2 * D) atomicAdd(&gstats[tid], sStat[tid]);
}

// ---------------- BN (training stats) + ReLU, in place; also emit bf16 copy
__global__ void bn_relu_bf(float* __restrict__ y, unsigned short* __restrict__ xb,
                           const float* __restrict__ stats,
                           const float* __restrict__ gamma, const float* __restrict__ beta,
                           int N) {
    int i = blockIdx.x * blockDim.x + threadIdx.x;
    int n4 = N * D / 4;
    if (i >= n4) return;
    int c0 = (i << 2) & (D - 1);
    float4 v = reinterpret_cast<float4*>(y)[i];
    float o[4] = {v.x, v.y, v.z, v.w};
    float invN = 1.0f / (float)N;
    #pragma unroll
    for (int j = 0; j < 4; j++) {
        int c = c0 + j;
        float mean = stats[c] * invN;
        float var  = stats[D + c] * invN - mean * mean;
        float sc = rsqrtf(var + BN_EPS) * gamma[c];
        float t = (o[j] - mean) * sc + beta[c];
        o[j] = fmaxf(t, 0.f);
    }
    float4 r; r.x = o[0]; r.y = o[1]; r.z = o[2]; r.w = o[3];
    reinterpret_cast<float4*>(y)[i] = r;
    uint2 ob;
    ob.x = (unsigned)f2bf(o[0]) | ((unsigned)f2bf(o[1]) << 16);
    ob.y = (unsigned)f2bf(o[2]) | ((unsigned)f2bf(o[3]) << 16);
    reinterpret_cast<uint2*>(xb)[i] = ob;
}

extern "C" void kernel_launch(void* const* d_in, const int* in_sizes, int n_in,
                              void* d_out, int out_size, void* d_ws, size_t ws_size,
                              hipStream_t stream) {
    const float* h     = (const float*)d_in[0];
    const int*   ei    = (const int*)d_in[1];
    const float* W1    = (const float*)d_in[2];
    const float* b1    = (const float*)d_in[3];
    const float* W2    = (const float*)d_in[4];
    const float* b2    = (const float*)d_in[5];
    const float* gamma = (const float*)d_in[6];
    const float* beta  = (const float*)d_in[7];
    float* out = (float*)d_out;

    const int N = in_sizes[0] / D;
    const int E = in_sizes[1] / 2;
    const int L = in_sizes[2] / (D * D);
    const int nb = (N + 255) / 256;

    // workspace layout
    unsigned short* zb  = (unsigned short*)d_ws;              // N*D bf16
    unsigned short* xb  = zb + (size_t)N * D;                 // N*D bf16
    unsigned short* Wt  = xb + (size_t)N * D;                 // 2L*128*128 bf16
    float* stats = (float*)(Wt + (size_t)2 * L * D * D);      // L*2*D floats
    int* cnt      = (int*)(stats + (size_t)L * 2 * D);        // N ints
    int* off      = cnt + N;                                  // N+1 ints
    int* bsum     = off + N + 1;                              // nb ints
    int* blockOff = bsum + nb;                                // nb ints
    int* rank     = blockOff + nb;                            // E ints
    void* eidx    = (void*)(rank + E);                        // E idx (ushort or int)

    const int* src = ei;
    const int* dst = ei + E;

    const int n4 = N * D / 4;
    const int n8 = N * D / 8;
    const int ewBlocks = (E + 255) / 256;
    const int gatherBlocks = 4 * ((N + 31) / 32);
    const int gemmBlocks = (N + 127) / 128;
    const int bnBlocks = (n4 + 255) / 256;
    const int wprepBlocks = (2 * L * D * D) / 256;
    const bool small = (N <= 65535);

    hipMemsetAsync(cnt, 0, N * sizeof(int), stream);
    hipMemsetAsync(stats, 0, (size_t)L * 2 * D * sizeof(float), stream);
    wprep<<<wprepBlocks, 256, 0, stream>>>(W1, W2, Wt, L);
    x2bf<<<(n8 + 255) / 256, 256, 0, stream>>>(h, xb, n8);

    // ---- CSR build (rank-based, atomic-free permute)
    hist_rank<<<ewBlocks, 256, 0, stream>>>(dst, cnt, rank, E);
    reduce_cnt<<<nb, 256, 0, stream>>>(cnt, bsum, N);
    scan_bsums<<<1, 256, 0, stream>>>(bsum, blockOff, off + N, nb);
    scan_partial<<<nb, 256, 0, stream>>>(cnt, off, blockOff, N);
    if (small)
        fill2<unsigned short><<<ewBlocks, 256, 0, stream>>>(src, dst, rank, off,
                                                            (unsigned short*)eidx, E);
    else
        fill2<int><<<ewBlocks, 256, 0, stream>>>(src, dst, rank, off, (int*)eidx, E);

    for (int l = 0; l < L; l++) {
        float* y = out + (size_t)l * N * D;

        if (small)
            gather_bf4<unsigned short><<<gatherBlocks, 256, 0, stream>>>(
                xb, off, (const unsigned short*)eidx, zb, N);
        else
            gather_bf4<int><<<gatherBlocks, 256, 0, stream>>>(
                xb, off, (const int*)eidx, zb, N);
        gemm1_mfma<<<gemmBlocks, 256, 0, stream>>>(zb, Wt + (size_t)l * D * D,
                                                   b1 + (size_t)l * D, zb, N);
        gemm2_mfma<<<gemmBlocks, 256, 0, stream>>>(zb, Wt + (size_t)(L + l) * D * D,
                                                   b2 + (size_t)l * D, y, stats + (size_t)l * 2 * D, N);
        bn_relu_bf<<<bnBlocks, 256, 0, stream>>>(y, xb, stats + (size_t)l * 2 * D,
                                                 gamma + (size_t)l * D, beta + (size_t)l * D, N);
    }
}

// Round 8
// 240.540 us; speedup vs baseline: 1.0864x; 1.0864x over previous
//
#include <hip/hip_runtime.h>

#define D 128
#define BN_EPS 1e-5f

typedef __attribute__((ext_vector_type(8))) short short8;
typedef __attribute__((ext_vector_type(4))) float f32x4;

// float -> bf16 bits, round-to-nearest-even
__device__ inline unsigned short f2bf(float f) {
    union { float f; unsigned int u; } v; v.f = f;
    unsigned int u = v.u;
    unsigned int r = (u + 0x7FFFu + ((u >> 16) & 1u)) >> 16;
    return (unsigned short)r;
}

__device__ inline float bfbits2f(unsigned int bits) {
    union { unsigned int u; float f; } v; v.u = bits;
    return v.f;
}

__device__ inline float4 bf2f4(uint2 v) {
    float4 r;
    r.x = bfbits2f(v.x << 16);
    r.y = bfbits2f(v.x & 0xFFFF0000u);
    r.z = bfbits2f(v.y << 16);
    r.w = bfbits2f(v.y & 0xFFFF0000u);
    return r;
}

// ------------------------------- histogram + per-edge rank (coalesced write)
__global__ void hist_rank(const int* __restrict__ dst, int* __restrict__ cnt,
                          int* __restrict__ rank, int E) {
    int e = blockIdx.x * blockDim.x + threadIdx.x;
    if (e >= E) return;
    rank[e] = atomicAdd(&cnt[dst[e]], 1);
}

// -------------------------------------------------- scan phase 1: per-block reduce
__global__ void reduce_cnt(const int* __restrict__ cnt, int* __restrict__ bsum, int n) {
    __shared__ int s[256];
    int tid = threadIdx.x;
    int i = blockIdx.x * 256 + tid;
    s[tid] = (i < n) ? cnt[i] : 0;
    __syncthreads();
    for (int ofs = 128; ofs > 0; ofs >>= 1) {
        if (tid < ofs) s[tid] += s[tid + ofs];
        __syncthreads();
    }
    if (tid == 0) bsum[blockIdx.x] = s[0];
}

// -------------------------------------------------- scan phase 2: scan block sums (1 block)
__global__ void scan_bsums(const int* __restrict__ bsum, int* __restrict__ blockOff,
                           int* __restrict__ offN, int nb) {
    __shared__ int s[256];
    int tid = threadIdx.x;
    int v = (tid < nb) ? bsum[tid] : 0;
    s[tid] = v;
    __syncthreads();
    for (int ofs = 1; ofs < 256; ofs <<= 1) {
        int t = (tid >= ofs) ? s[tid - ofs] : 0;
        __syncthreads();
        s[tid] += t;
        __syncthreads();
    }
    if (tid < nb) blockOff[tid] = s[tid] - v;
    if (tid == nb - 1) *offN = s[tid];
}

// -------------------------------------------------- scan phase 3: per-block scan + offset
__global__ void scan_partial(const int* __restrict__ cnt, int* __restrict__ off,
                             const int* __restrict__ blockOff, int n) {
    __shared__ int s[256];
    int tid = threadIdx.x;
    int i = blockIdx.x * 256 + tid;
    int v = (i < n) ? cnt[i] : 0;
    s[tid] = v;
    __syncthreads();
    for (int ofs = 1; ofs < 256; ofs <<= 1) {
        int t = (tid >= ofs) ? s[tid - ofs] : 0;
        __syncthreads();
        s[tid] += t;
        __syncthreads();
    }
    if (i < n) off[i] = blockOff[blockIdx.x] + s[tid] - v;
}

// -------------------------------------------------- CSR fill (no atomics)
template<typename IdxT>
__global__ void fill2(const int* __restrict__ src, const int* __restrict__ dst,
                      const int* __restrict__ rank, const int* __restrict__ off,
                      IdxT* __restrict__ eidx, int E) {
    int e = blockIdx.x * blockDim.x + threadIdx.x;
    if (e >= E) return;
    eidx[off[dst[e]] + rank[e]] = (IdxT)src[e];
}

// ------------------------- weight prep: Wt[m][n][k] = bf16(W[m][k][n]), m = 2L mats
__global__ void wprep(const float* __restrict__ W1, const float* __restrict__ W2,
                      unsigned short* __restrict__ Wt, int L) {
    int idx = blockIdx.x * 256 + threadIdx.x;
    int m = idx >> 14;
    int rem = idx & 16383;
    int c = rem >> 7, k = rem & 127;
    const float* W = (m < L) ? (W1 + (size_t)m * D * D) : (W2 + (size_t)(m - L) * D * D);
    Wt[(size_t)m * D * D + c * D + k] = f2bf(W[k * D + c]);
}

// -------------------------------------------------- h (fp32) -> xb (bf16)
__global__ void x2bf(const float* __restrict__ x, unsigned short* __restrict__ xb, int n8) {
    int i = blockIdx.x * 256 + threadIdx.x;
    if (i >= n8) return;
    float4 a = reinterpret_cast<const float4*>(x)[2 * i];
    float4 b = reinterpret_cast<const float4*>(x)[2 * i + 1];
    uint4 o;
    o.x = (unsigned)f2bf(a.x) | ((unsigned)f2bf(a.y) << 16);
    o.y = (unsigned)f2bf(a.z) | ((unsigned)f2bf(a.w) << 16);
    o.z = (unsigned)f2bf(b.x) | ((unsigned)f2bf(b.y) << 16);
    o.w = (unsigned)f2bf(b.z) | ((unsigned)f2bf(b.w) << 16);
    reinterpret_cast<uint4*>(xb)[i] = o;
}

// ------------------------------ z_i = x_i + sum_{j in N(i)} x_j, bf16 in / bf16 out
// 32 lanes per node (uint2 = 8B per lane covers a full 256B row per iteration).
template<typename IdxT>
__global__ __launch_bounds__(256) void gather_bf(
        const unsigned short* __restrict__ xb, const int* __restrict__ off,
        const IdxT* __restrict__ eidx, unsigned short* __restrict__ zb, int N) {
    int t = blockIdx.x * blockDim.x + threadIdx.x;
    int node = t >> 5;
    if (node >= N) return;
    int lane = t & 31;
    int beg = off[node], end = off[node + 1];
    float4 acc = bf2f4(*reinterpret_cast<const uint2*>(xb + (size_t)node * D + lane * 4));
    int e = beg;
    for (; e + 2 <= end; e += 2) {
        int s0 = (int)eidx[e], s1 = (int)eidx[e + 1];
        uint2 v0 = *reinterpret_cast<const uint2*>(xb + (size_t)s0 * D + lane * 4);
        uint2 v1 = *reinterpret_cast<const uint2*>(xb + (size_t)s1 * D + lane * 4);
        float4 f0 = bf2f4(v0), f1 = bf2f4(v1);
        acc.x += f0.x + f1.x; acc.y += f0.y + f1.y;
        acc.z += f0.z + f1.z; acc.w += f0.w + f1.w;
    }
    if (e < end) {
        int s0 = (int)eidx[e];
        float4 f0 = bf2f4(*reinterpret_cast<const uint2*>(xb + (size_t)s0 * D + lane * 4));
        acc.x += f0.x; acc.y += f0.y; acc.z += f0.z; acc.w += f0.w;
    }
    uint2 o;
    o.x = (unsigned)f2bf(acc.x) | ((unsigned)f2bf(acc.y) << 16);
    o.y = (unsigned)f2bf(acc.z) | ((unsigned)f2bf(acc.w) << 16);
    *reinterpret_cast<uint2*>(zb + (size_t)node * D + lane * 4) = o;
}

// ------------- MFMA GEMM1, no LDS: zb = relu(zb@W1 + b1), 128 rows/block,
// 4 waves x 2 row-tiles; B-fragments stream from L2 (Wt is 32KB, grid-broadcast).
__global__ __launch_bounds__(256) void gemm1_mfma(
        const unsigned short* __restrict__ A, const unsigned short* __restrict__ Wt,
        const float* __restrict__ bias, unsigned short* __restrict__ Out, int N) {
    const int tid = threadIdx.x;
    const int lane = tid & 63, wv = tid >> 6;
    const int r0 = blockIdx.x * 128 + wv * 32;
    const int koff = (lane >> 4) << 3;
    const int col = lane & 15;

    int ar0 = r0 + col;       if (ar0 >= N) ar0 = N - 1;
    int ar1 = r0 + 16 + col;  if (ar1 >= N) ar1 = N - 1;
    const unsigned short* ap0 = A + (size_t)ar0 * D + koff;
    const unsigned short* ap1 = A + (size_t)ar1 * D + koff;
    const unsigned short* wp  = Wt + (size_t)col * D + koff;

    f32x4 acc[2][8];
    #pragma unroll
    for (int ct = 0; ct < 8; ct++) {
        float b = bias[ct * 16 + col];
        acc[0][ct] = (f32x4){b, b, b, b};
        acc[1][ct] = (f32x4){b, b, b, b};
    }
    #pragma unroll
    for (int ks = 0; ks < 4; ks++) {
        short8 a0 = *reinterpret_cast<const short8*>(ap0 + ks * 32);
        short8 a1 = *reinterpret_cast<const short8*>(ap1 + ks * 32);
        #pragma unroll
        for (int ct = 0; ct < 8; ct++) {
            short8 bfr = *reinterpret_cast<const short8*>(wp + (size_t)ct * 16 * D + ks * 32);
            acc[0][ct] = __builtin_amdgcn_mfma_f32_16x16x32_bf16(a0, bfr, acc[0][ct], 0, 0, 0);
            acc[1][ct] = __builtin_amdgcn_mfma_f32_16x16x32_bf16(a1, bfr, acc[1][ct], 0, 0, 0);
        }
    }
    #pragma unroll
    for (int t = 0; t < 2; t++) {
        #pragma unroll
        for (int ct = 0; ct < 8; ct++) {
            #pragma unroll
            for (int r = 0; r < 4; r++) {
                int row = r0 + t * 16 + ((lane >> 4) << 2) + r;
                if (row < N)
                    Out[(size_t)row * D + ct * 16 + col] = f2bf(fmaxf(acc[t][ct][r], 0.f));
            }
        }
    }
}

// ------------- MFMA GEMM2, no LDS: y = zb@W2 + b2 (fp32 out) + column stats
__global__ __launch_bounds__(256) void gemm2_mfma(
        const unsigned short* __restrict__ A, const unsigned short* __restrict__ Wt,
        const float* __restrict__ bias, float* __restrict__ Out,
        float* __restrict__ gstats, int N) {
    __shared__ float sStat[2 * D];
    const int tid = threadIdx.x;
    if (tid < 2 * D) sStat[tid] = 0.f;
    __syncthreads();

    const int lane = tid & 63, wv = tid >> 6;
    const int r0 = blockIdx.x * 128 + wv * 32;
    const int koff = (lane >> 4) << 3;
    const int col = lane & 15;

    int ar0 = r0 + col;       if (ar0 >= N) ar0 = N - 1;
    int ar1 = r0 + 16 + col;  if (ar1 >= N) ar1 = N - 1;
    const unsigned short* ap0 = A + (size_t)ar0 * D + koff;
    const unsigned short* ap1 = A + (size_t)ar1 * D + koff;
    const unsigned short* wp  = Wt + (size_t)col * D + koff;

    f32x4 acc[2][8];
    #pragma unroll
    for (int ct = 0; ct < 8; ct++) {
        float b = bias[ct * 16 + col];
        acc[0][ct] = (f32x4){b, b, b, b};
        acc[1][ct] = (f32x4){b, b, b, b};
    }
    #pragma unroll
    for (int ks = 0; ks < 4; ks++) {
        short8 a0 = *reinterpret_cast<const short8*>(ap0 + ks * 32);
        short8 a1 = *reinterpret_cast<const short8*>(ap1 + ks * 32);
        #pragma unroll
        for (int ct = 0; ct < 8; ct++) {
            short8 bfr = *reinterpret_cast<const short8*>(wp + (size_t)ct * 16 * D + ks * 32);
            acc[0][ct] = __builtin_amdgcn_mfma_f32_16x16x32_bf16(a0, bfr, acc[0][ct], 0, 0, 0);
            acc[1][ct] = __builtin_amdgcn_mfma_f32_16x16x32_bf16(a1, bfr, acc[1][ct], 0, 0, 0);
        }
    }
    #pragma unroll
    for (int ct = 0; ct < 8; ct++) {
        float s = 0.f, q = 0.f;
        #pragma unroll
        for (int t = 0; t < 2; t++) {
            #pragma unroll
            for (int r = 0; r < 4; r++) {
                int row = r0 + t * 16 + ((lane >> 4) << 2) + r;
                float v = acc[t][ct][r];
                if (row < N) {
                    Out[(size_t)row * D + ct * 16 + col] = v;
                    s += v; q += v * v;
                }
            }
        }
        s += __shfl_xor(s, 16); q += __shfl_xor(q, 16);
        s += __shfl_xor(s, 32); q += __shfl_xor(q, 32);
        if (lane < 16) {
            atomicAdd(&sStat[ct * 16 + lane], s);
            atomicAdd(&sStat[D + ct * 16 + lane], q);
        }
    }
    __syncthreads();
    if (tid < 2 * D) atomicAdd(&gstats[tid], sStat[tid]);
}

// ---------------- BN (training stats) + ReLU, in place; optionally emit bf16 copy
__global__ void bn_relu_bf(float* __restrict__ y, unsigned short* __restrict__ xb,
                           const float* __restrict__ stats,
                           const float* __restrict__ gamma, const float* __restrict__ beta,
                           int N, int emit_bf) {
    int i = blockIdx.x * blockDim.x + threadIdx.x;
    int n4 = N * D / 4;
    if (i >= n4) return;
    int c0 = (i << 2) & (D - 1);
    float4 v = reinterpret_cast<float4*>(y)[i];
    float o[4] = {v.x, v.y, v.z, v.w};
    float invN = 1.0f / (float)N;
    #pragma unroll
    for (int j = 0; j < 4; j++) {
        int c = c0 + j;
        float mean = stats[c] * invN;
        float var  = stats[D + c] * invN - mean * mean;
        float sc = rsqrtf(var + BN_EPS) * gamma[c];
        float t = (o[j] - mean) * sc + beta[c];
        o[j] = fmaxf(t, 0.f);
    }
    float4 r; r.x = o[0]; r.y = o[1]; r.z = o[2]; r.w = o[3];
    reinterpret_cast<float4*>(y)[i] = r;
    if (emit_bf) {
        uint2 ob;
        ob.x = (unsigned)f2bf(o[0]) | ((unsigned)f2bf(o[1]) << 16);
        ob.y = (unsigned)f2bf(o[2]) | ((unsigned)f2bf(o[3]) << 16);
        reinterpret_cast<uint2*>(xb)[i] = ob;
    }
}

extern "C" void kernel_launch(void* const* d_in, const int* in_sizes, int n_in,
                              void* d_out, int out_size, void* d_ws, size_t ws_size,
                              hipStream_t stream) {
    const float* h     = (const float*)d_in[0];
    const int*   ei    = (const int*)d_in[1];
    const float* W1    = (const float*)d_in[2];
    const float* b1    = (const float*)d_in[3];
    const float* W2    = (const float*)d_in[4];
    const float* b2    = (const float*)d_in[5];
    const float* gamma = (const float*)d_in[6];
    const float* beta  = (const float*)d_in[7];
    float* out = (float*)d_out;

    const int N = in_sizes[0] / D;
    const int E = in_sizes[1] / 2;
    const int L = in_sizes[2] / (D * D);
    const int nb = (N + 255) / 256;

    // workspace layout
    unsigned short* zb  = (unsigned short*)d_ws;              // N*D bf16
    unsigned short* xb  = zb + (size_t)N * D;                 // N*D bf16
    unsigned short* Wt  = xb + (size_t)N * D;                 // 2L*128*128 bf16
    float* stats = (float*)(Wt + (size_t)2 * L * D * D);      // L*2*D floats
    int* cnt      = (int*)(stats + (size_t)L * 2 * D);        // N ints
    int* off      = cnt + N;                                  // N+1 ints
    int* bsum     = off + N + 1;                              // nb ints
    int* blockOff = bsum + nb;                                // nb ints
    int* rank     = blockOff + nb;                            // E ints
    void* eidx    = (void*)(rank + E);                        // E idx (ushort or int)

    const int* src = ei;
    const int* dst = ei + E;

    const int n4 = N * D / 4;
    const int n8 = N * D / 8;
    const int ewBlocks = (E + 255) / 256;
    const int gatherBlocks = (N * 32 + 255) / 256;
    const int gemmBlocks = (N + 127) / 128;
    const int bnBlocks = (n4 + 255) / 256;
    const int wprepBlocks = (2 * L * D * D) / 256;
    const bool small = (N <= 65535);

    hipMemsetAsync(cnt, 0, N * sizeof(int), stream);
    hipMemsetAsync(stats, 0, (size_t)L * 2 * D * sizeof(float), stream);
    wprep<<<wprepBlocks, 256, 0, stream>>>(W1, W2, Wt, L);
    x2bf<<<(n8 + 255) / 256, 256, 0, stream>>>(h, xb, n8);

    // ---- CSR build (rank-based, atomic-free permute)
    hist_rank<<<ewBlocks, 256, 0, stream>>>(dst, cnt, rank, E);
    reduce_cnt<<<nb, 256, 0, stream>>>(cnt, bsum, N);
    scan_bsums<<<1, 256, 0, stream>>>(bsum, blockOff, off + N, nb);
    scan_partial<<<nb, 256, 0, stream>>>(cnt, off, blockOff, N);
    if (small)
        fill2<unsigned short><<<ewBlocks, 256, 0, stream>>>(src, dst, rank, off,
                                                            (unsigned short*)eidx, E);
    else
        fill2<int><<<ewBlocks, 256, 0, stream>>>(src, dst, rank, off, (int*)eidx, E);

    for (int l = 0; l < L; l++) {
        float* y = out + (size_t)l * N * D;

        if (small)
            gather_bf<unsigned short><<<gatherBlocks, 256, 0, stream>>>(
                xb, off, (const unsigned short*)eidx, zb, N);
        else
            gather_bf<int><<<gatherBlocks, 256, 0, stream>>>(
                xb, off, (const int*)eidx, zb, N);
        gemm1_mfma<<<gemmBlocks, 256, 0, stream>>>(zb, Wt + (size_t)l * D * D,
                                                   b1 + (size_t)l * D, zb, N);
        gemm2_mfma<<<gemmBlocks, 256, 0, stream>>>(zb, Wt + (size_t)(L + l) * D * D,
                                                   b2 + (size_t)l * D, y, stats + (size_t)l * 2 * D, N);
        bn_relu_bf<<<bnBlocks, 256, 0, stream>>>(y, xb, stats + (size_t)l * 2 * D,
                                                 gamma + (size_t)l * D, beta + (size_t)l * D,
                                                 N, (l + 1 < L) ? 1 : 0);
    }
}